// Round 10
// baseline (226.312 us; speedup 1.0000x reference)
//
#include <hip/hip_runtime.h>
#include <hip/hip_bf16.h>
#include <hip/hip_cooperative_groups.h>

namespace cg = cooperative_groups;

#define Bt 16
#define Ct 16
#define Nt 64
#define KITERt 4

// ---------- fp32 weight block offsets (floats) ----------
// wq@0(512) bq@512(32) wk@544(512) bk@1056(32) wm@1088(2304) bm@3392(16)
// w1@3408(4096) b1@7504(64) w2@7568(4096) b2@11664(64) wo@11728(64) bo@11792(1)
// gb@11793(16) wg@11809(9216) bg@21025(32) wc@21057(4608) bc@25665(16)
#define WF_TOTAL 25681
#define SWZ_TOTAL 16384
#define SETUP_IDX (WF_TOTAL + 4096 + Nt + SWZ_TOTAL)
#define SAH_STRIDE 40

typedef __attribute__((ext_vector_type(8))) short bf16x8;
typedef __attribute__((ext_vector_type(4))) short s16x4;
typedef __attribute__((ext_vector_type(4))) float f32x4;

__device__ inline short f2bs(float f) {
    __hip_bfloat16 h = __float2bfloat16(f);
    short s; __builtin_memcpy(&s, &h, 2); return s;
}
__device__ inline float bs2f(short s) {
    __hip_bfloat16 h; __builtin_memcpy(&h, &s, 2);
    return __bfloat162float(h);
}
__device__ inline float loadf(const void* p, int i, int isf32) {
    return isf32 ? ((const float*)p)[i]
                 : __bfloat162float(((const __hip_bfloat16*)p)[i]);
}
__device__ inline float sigm(float x) {
    return __builtin_amdgcn_rcpf(1.f + __expf(-x));
}
__device__ inline float tanh_fast(float x) {
    float e = __expf(2.f * x);
    return 1.f - 2.f * __builtin_amdgcn_rcpf(e + 1.f);
}

// ======================= SETUP (R3, verified; normal dispatch) ============
__global__ __launch_bounds__(256) void setup_kernel(
    const void* __restrict__ seed,
    const void* __restrict__ wq, const void* __restrict__ bq,
    const void* __restrict__ wk, const void* __restrict__ bk,
    const void* __restrict__ wm, const void* __restrict__ bm,
    const void* __restrict__ w1, const void* __restrict__ b1,
    const void* __restrict__ w2, const void* __restrict__ b2,
    const void* __restrict__ wo, const void* __restrict__ bo,
    const void* __restrict__ gw, const void* __restrict__ gb,
    const void* __restrict__ wg, const void* __restrict__ bg,
    const void* __restrict__ wc, const void* __restrict__ bc,
    const int* __restrict__ edge, int E,
    float* __restrict__ Wf, float* __restrict__ Tpix,
    int* __restrict__ counts, int* __restrict__ nbrs,
    __hip_bfloat16* __restrict__ swz,
    short* __restrict__ Xb, float* __restrict__ qv0, float* __restrict__ kv0,
    float* __restrict__ M0,
    int* __restrict__ flag)
{
    __shared__ float sred[4];
    __shared__ int sflag;
    __shared__ float xred[64];
    __shared__ int snb[256];
    __shared__ __align__(16) short sM[324 * SAH_STRIDE];
    int bn = blockIdx.x, t = threadIdx.x;
    int lane = t & 63, wv = t >> 6;
    int quad = lane >> 4, n16 = lane & 15;

    {
        float v = fabsf(__bfloat162float(((const __hip_bfloat16*)seed)[t]));
        if (!(v <= 1e30f)) v = 1e30f;
#pragma unroll
        for (int off = 1; off < 64; off <<= 1) v = fmaxf(v, __shfl_xor(v, off, 64));
        if (lane == 0) sred[wv] = v;
        __syncthreads();
        if (t == 0) {
            float m = fmaxf(fmaxf(sred[0], sred[1]), fmaxf(sred[2], sred[3]));
            sflag = (m > 1e10f) ? 1 : 0;
            if (bn == 0) *flag = sflag;
        }
        __syncthreads();
    }
    int isf32 = sflag;

    if (bn == 0) {
        snb[t] = 0;
        __syncthreads();
        for (int e = t; e < E; e += 256) {
            int ei = edge[2 * e], ej = edge[2 * e + 1];
            int d = ej - ei;
            int slot = (d == 1) ? 0 : (d == 8) ? 1 : (d == -1) ? 2 : 3;
            snb[ei * 4 + slot] = ej + 1;
        }
        __syncthreads();
        if (t < 64) {
            int dcount = 0;
            int outv[4] = {0, 0, 0, 0};
#pragma unroll
            for (int s = 0; s < 4; ++s) {
                int v = snb[t * 4 + s];
                if (v) outv[dcount++] = v - 1;
            }
            counts[t] = dcount;
#pragma unroll
            for (int s = 0; s < 4; ++s) nbrs[t * 4 + s] = outv[s];
        }
    }

    int idx = bn * 256 + t;
    if (idx < WF_TOTAL) {
        int i = idx;
        const void* base;
        if (i < 512) base = wq;
        else if ((i -= 512) < 32) base = bq;
        else if ((i -= 32) < 512) base = wk;
        else if ((i -= 512) < 32) base = bk;
        else if ((i -= 32) < 2304) base = wm;
        else if ((i -= 2304) < 16) base = bm;
        else if ((i -= 16) < 4096) base = w1;
        else if ((i -= 4096) < 64) base = b1;
        else if ((i -= 64) < 4096) base = w2;
        else if ((i -= 4096) < 64) base = b2;
        else if ((i -= 64) < 64) base = wo;
        else if ((i -= 64) < 1) base = bo;
        else if ((i -= 1) < 16) base = gb;
        else if ((i -= 16) < 9216) base = wg;
        else if ((i -= 9216) < 32) base = bg;
        else if ((i -= 32) < 4608) base = wc;
        else { i -= 4608; base = bc; }
        Wf[idx] = loadf(base, i, isf32);
    } else if (idx < WF_TOTAL + 4096) {
        int j = idx - WF_TOTAL;
        int pix = j >> 4, ch = j & 15;
        int y = pix >> 4, x = pix & 15;
        float s = 0.f;
        for (int ky = 0; ky < 3; ++ky)
            for (int kx = 0; kx < 3; ++kx) {
                int yy = y + ky - 1, xx = x + kx - 1;
                if (yy >= 0 && yy < 16 && xx >= 0 && xx < 16)
                    s += loadf(gw, ch * 9 + ky * 3 + kx, isf32);
            }
        Tpix[j] = s;
    } else if (idx >= WF_TOTAL + 4096 + Nt && idx < SETUP_IDX) {
        int j = idx - (WF_TOTAL + 4096 + Nt);
        float val;
        if (j < 9216) {
            int sn = j >> 9, rem = j & 511;
            int ln = rem >> 3, jj = rem & 7;
            int s = sn >> 1, nt = sn & 1;
            int ci = (ln >> 4) * 8 + jj;
            int co = nt * 16 + (ln & 15);
            val = loadf(wg, co * 288 + ci * 9 + s, isf32);
        } else if (j < 9216 + 4608) {
            int j1 = j - 9216;
            int s = j1 >> 9, rem = j1 & 511;
            int ln = rem >> 3, jj = rem & 7;
            int ci = (ln >> 4) * 8 + jj;
            int co = ln & 15;
            val = loadf(wc, co * 288 + ci * 9 + s, isf32);
        } else {
            int j2 = j - 13824;
            int sp = j2 >> 9, rem = j2 & 511;
            int ln = rem >> 3, jj = rem & 7;
            int k = (ln >> 4) * 8 + jj;
            int s = sp * 2 + (k >> 4);
            int ci = k & 15;
            int co = ln & 15;
            val = (s <= 8) ? loadf(wm, co * 144 + ci * 9 + s, isf32) : 0.f;
        }
        swz[j] = __float2bfloat16(val);
    }

    {
        int b = bn >> 6, n = bn & 63;
        int pq = n >> 3, qq = n & 7;
        int y = t >> 4, x = t & 15;
        float v[16];
#pragma unroll
        for (int c = 0; c < 16; ++c)
            v[c] = loadf(seed, ((b * 16 + c) * 128 + pq * 16 + y) * 128 + qq * 16 + x, isf32);
        bf16x8 o0, o1;
#pragma unroll
        for (int c = 0; c < 8; ++c) { o0[c] = f2bs(v[c]); o1[c] = f2bs(v[8 + c]); }
        short* xo = Xb + bn * 4096;
        *(bf16x8*)(xo + t * 16) = o0;
        *(bf16x8*)(xo + t * 16 + 8) = o1;

        for (int p = t; p < 324; p += 256) {
            int yy = p / 18 - 1, xx = p % 18 - 1;
            if (!((unsigned)yy < 16u && (unsigned)xx < 16u)) {
                bf16x8 z = {0, 0, 0, 0, 0, 0, 0, 0};
                *(bf16x8*)(sM + p * SAH_STRIDE) = z;
                *(bf16x8*)(sM + p * SAH_STRIDE + 8) = z;
            }
        }
        int pp = ((t >> 4) + 1) * 18 + (t & 15) + 1;
        *(bf16x8*)(sM + pp * SAH_STRIDE) = o0;
        *(bf16x8*)(sM + pp * SAH_STRIDE + 8) = o1;

#pragma unroll
        for (int c = 0; c < 16; ++c) {
            float s = v[c];
#pragma unroll
            for (int off = 1; off < 64; off <<= 1) s += __shfl_xor(s, off, 64);
            if (lane == c) xred[wv * 16 + c] = s;
        }
        __syncthreads();
        if (t < 64) {
            int d = t & 31;
            float a = (t < 32) ? loadf(bq, d, isf32) : loadf(bk, d, isf32);
#pragma unroll
            for (int c = 0; c < 16; ++c) {
                float xm = (xred[c] + xred[16 + c] + xred[32 + c] + xred[48 + c]) * (1.f / 256.f);
                a += xm * ((t < 32) ? loadf(wq, c * 32 + d, isf32)
                                    : loadf(wk, c * 32 + d, isf32));
            }
            if (t < 32) qv0[bn * 32 + d] = a; else kv0[bn * 32 + d] = a;
        }

        float bm_l = loadf(bm, n16, isf32);
        f32x4 accM[4];
#pragma unroll
        for (int mt = 0; mt < 4; ++mt) accM[mt] = (f32x4){bm_l, bm_l, bm_l, bm_l};
#pragma unroll
        for (int sp = 0; sp < 5; ++sp) {
            int s2 = sp * 2 + (quad >> 1);
            int valid = (s2 <= 8);
            int s2c = valid ? s2 : 8;
            int ky = s2c / 3, kx = s2c - ky * 3;
            bf16x8 Bf;
#pragma unroll
            for (int j = 0; j < 8; ++j) {
                short bv = 0;
                if (valid) bv = f2bs(loadf(wm, n16 * 144 + ((quad & 1) * 8 + j) * 9 + s2, isf32));
                Bf[j] = bv;
            }
            int cib = (quad & 1) * 8;
#pragma unroll
            for (int mt = 0; mt < 4; ++mt) {
                int pc = (wv * 4 + mt + ky) * 18 + n16 + kx;
                bf16x8 A = *(const bf16x8*)(sM + pc * SAH_STRIDE + cib);
                accM[mt] = __builtin_amdgcn_mfma_f32_16x16x32_bf16(A, Bf, accM[mt], 0, 0, 0);
            }
        }
        float* mo = M0 + bn * 4096;
#pragma unroll
        for (int mt = 0; mt < 4; ++mt)
#pragma unroll
            for (int r = 0; r < 4; ++r) {
                int pix = (wv * 4 + mt) * 16 + quad * 4 + r;
                mo[pix * 16 + n16] = accM[mt][r];
            }
    }
}

// ============== COOPERATIVE 4-ITERATION KERNEL (no setup code) ============
// R10: (1) launch_bounds(256,4) -- the EXACT attribute under which this loop
// body (iter_kernel, R3) compiles spill-free and runs at ~33us; with the
// unroll-1 pragmas the iter4 body matches it. (2) Guard no longer consults
// prop.cooperativeLaunch: R4 empirically proved hipLaunchCooperativeKernel
// executes on this stack (some ROCm builds report the flag as 0 regardless),
// and that flag was common to ALL four failed guards (R6-R9). Safety now
// rests on measured facts only: numRegs<=128 => 4 blocks/CU => 1024-block
// grid exactly co-resident (R4 proved acceptance at this LDS/grid shape);
// localSizeBytes==0 => no R4 spill pathology.
__global__ __launch_bounds__(256, 4)
void iter4_kernel(
    const short* __restrict__ Xin,
    float* __restrict__ Mb0, float* __restrict__ Mb1,
    float* __restrict__ qv0, float* __restrict__ kv0,
    float* __restrict__ qv1, float* __restrict__ kv1,
    const float* __restrict__ Tpix,
    const short* __restrict__ WmS,
    const short* __restrict__ WgS,
    const short* __restrict__ WcS,
    const float* __restrict__ Wf,
    const int* __restrict__ counts, const int* __restrict__ nbrs,
    const int* __restrict__ flagp, void* __restrict__ out)
{
    __shared__ __align__(16) short sAH[324 * SAH_STRIDE];  // ch0-15 Magg/nx, ch16-31 h/rh
    __shared__ float evs[4];
    __shared__ float xred[64];
    int bn = blockIdx.x, b = bn >> 6, i = bn & 63;
    int t = threadIdx.x, lane = t & 63, wv = t >> 6;
    int quad = lane >> 4, n16 = lane & 15;
    int pp = ((t >> 4) + 1) * 18 + (t & 15) + 1;

    int4 nb4 = *(const int4*)(nbrs + i * 4);
    int deg = counts[i];
    int ejl[4] = {nb4.x, nb4.y, nb4.z, nb4.w};

    // ---- phase A (ONCE): stage own h into ch16-31; zero all borders ----
    const short* xown = Xin + bn * 4096;
    for (int p = t; p < 324; p += 256) {
        int yy = p / 18 - 1, xx = p % 18 - 1;
        short* row = sAH + p * SAH_STRIDE;
        if ((unsigned)yy < 16u && (unsigned)xx < 16u) {
            const short* src = xown + (yy * 16 + xx) * 16;
            *(bf16x8*)(row + 16) = *(const bf16x8*)(src);
            *(bf16x8*)(row + 24) = *(const bf16x8*)(src + 8);
        } else {
            bf16x8 z = {0, 0, 0, 0, 0, 0, 0, 0};
            *(bf16x8*)(row) = z;      *(bf16x8*)(row + 8) = z;
            *(bf16x8*)(row + 16) = z; *(bf16x8*)(row + 24) = z;
        }
    }

#pragma unroll 1
    for (int it = 0; it < KITERt; ++it) {
        const float* Min  = (it & 1) ? Mb1 : Mb0;
        float*       Mout = (it & 1) ? Mb0 : Mb1;
        const float* qin  = (it & 1) ? qv1 : qv0;
        const float* kin  = (it & 1) ? kv1 : kv0;
        float*       qout = (it & 1) ? qv0 : qv1;
        float*       kout = (it & 1) ? kv0 : kv1;
        int last = (it == KITERt - 1);

        // ---- phase B: edge MLP ----
        if (wv < deg) {
            int ej = ejl[wv];
            float h0 = (lane < 32) ? qin[bn * 32 + lane]
                                   : kin[(b * 64 + ej) * 32 + (lane - 32)];
            const float* W1 = Wf + 3408;
            const float* W2 = Wf + 7568;
            float p0 = 0.f, p1 = 0.f, p2 = 0.f, p3 = 0.f;
#pragma unroll
            for (int j = 0; j < 64; j += 4) {
                p0 += __shfl(h0, j + 0, 64) * W1[(j + 0) * 64 + lane];
                p1 += __shfl(h0, j + 1, 64) * W1[(j + 1) * 64 + lane];
                p2 += __shfl(h0, j + 2, 64) * W1[(j + 2) * 64 + lane];
                p3 += __shfl(h0, j + 3, 64) * W1[(j + 3) * 64 + lane];
            }
            float a1 = fmaxf(Wf[7504 + lane] + ((p0 + p1) + (p2 + p3)), 0.f);
            p0 = p1 = p2 = p3 = 0.f;
#pragma unroll
            for (int j = 0; j < 64; j += 4) {
                p0 += __shfl(a1, j + 0, 64) * W2[(j + 0) * 64 + lane];
                p1 += __shfl(a1, j + 1, 64) * W2[(j + 1) * 64 + lane];
                p2 += __shfl(a1, j + 2, 64) * W2[(j + 2) * 64 + lane];
                p3 += __shfl(a1, j + 3, 64) * W2[(j + 3) * 64 + lane];
            }
            float a2 = fmaxf(Wf[11664 + lane] + ((p0 + p1) + (p2 + p3)), 0.f);
            float pe = a2 * Wf[11728 + lane];
#pragma unroll
            for (int off = 32; off; off >>= 1) pe += __shfl_down(pe, off, 64);
            if (lane == 0) evs[wv] = pe + Wf[11792];
        }
        __syncthreads();

        // ---- phase C: gated aggregation of neighbor M (unroll 1: one
        // neighbor's 16 regs in flight at a time, not 64) ----
        float magg[16];
#pragma unroll
        for (int c = 0; c < 16; ++c) magg[c] = 0.f;
        {
            float Tp[16];
#pragma unroll
            for (int c = 0; c < 4; ++c)
                *(f32x4*)(Tp + 4 * c) = *(const f32x4*)(Tpix + t * 16 + 4 * c);
#pragma unroll 1
            for (int ii = 0; ii < 4; ++ii)
                if (ii < deg) {
                    const float* mp = Min + (b * 64 + ejl[ii]) * 4096 + t * 16;
                    f32x4 m0 = *(const f32x4*)(mp);
                    f32x4 m1 = *(const f32x4*)(mp + 4);
                    f32x4 m2 = *(const f32x4*)(mp + 8);
                    f32x4 m3 = *(const f32x4*)(mp + 12);
                    float evv = evs[ii];
#pragma unroll
                    for (int c = 0; c < 4; ++c) {
                        magg[c]      += sigm(evv * Tp[c]      + Wf[11793 + c])      * m0[c];
                        magg[c + 4]  += sigm(evv * Tp[c + 4]  + Wf[11793 + c + 4])  * m1[c];
                        magg[c + 8]  += sigm(evv * Tp[c + 8]  + Wf[11793 + c + 8])  * m2[c];
                        magg[c + 12] += sigm(evv * Tp[c + 12] + Wf[11793 + c + 12]) * m3[c];
                    }
                }
        }
        {
            bf16x8 mg0, mg1;
#pragma unroll
            for (int c = 0; c < 8; ++c) { mg0[c] = f2bs(magg[c]); mg1[c] = f2bs(magg[c + 8]); }
            *(bf16x8*)(sAH + pp * SAH_STRIDE) = mg0;
            *(bf16x8*)(sAH + pp * SAH_STRIDE + 8) = mg1;
        }
        __syncthreads();

        // ---- zr conv ----
        float bz = Wf[21025 + n16], br = Wf[21025 + 16 + n16];
        f32x4 accZ[4], accR[4];
#pragma unroll
        for (int mt = 0; mt < 4; ++mt) {
            accZ[mt] = (f32x4){bz, bz, bz, bz};
            accR[mt] = (f32x4){br, br, br, br};
        }
#pragma unroll
        for (int s = 0; s < 9; ++s) {
            int ky = s / 3, kx = s - (s / 3) * 3;
            bf16x8 B0 = *(const bf16x8*)(WgS + (s * 2 + 0) * 512 + lane * 8);
            bf16x8 B1 = *(const bf16x8*)(WgS + (s * 2 + 1) * 512 + lane * 8);
#pragma unroll
            for (int mt = 0; mt < 4; ++mt) {
                int pc = (wv * 4 + mt + ky) * 18 + n16 + kx;
                bf16x8 A = *(const bf16x8*)(sAH + pc * SAH_STRIDE + quad * 8);
                accZ[mt] = __builtin_amdgcn_mfma_f32_16x16x32_bf16(A, B0, accZ[mt], 0, 0, 0);
                accR[mt] = __builtin_amdgcn_mfma_f32_16x16x32_bf16(A, B1, accR[mt], 0, 0, 0);
            }
        }
        float zf[16], hf[16], rh[16];
#pragma unroll
        for (int mt = 0; mt < 4; ++mt)
#pragma unroll
            for (int r = 0; r < 4; ++r) {
                int k = mt * 4 + r;
                int ps = (wv * 4 + mt + 1) * 18 + quad * 4 + r + 1;
                hf[k] = bs2f(sAH[ps * SAH_STRIDE + 16 + n16]);
                zf[k] = sigm(accZ[mt][r]);
                rh[k] = sigm(accR[mt][r]) * hf[k];
            }
        __syncthreads();
#pragma unroll
        for (int mt = 0; mt < 4; ++mt)
#pragma unroll
            for (int r = 0; r < 4; ++r) {
                int ps = (wv * 4 + mt + 1) * 18 + quad * 4 + r + 1;
                sAH[ps * SAH_STRIDE + 16 + n16] = f2bs(rh[mt * 4 + r]);
            }
        __syncthreads();

        // ---- cand conv ----
        float bcl = Wf[25665 + n16];
        f32x4 accC[4];
#pragma unroll
        for (int mt = 0; mt < 4; ++mt) accC[mt] = (f32x4){bcl, bcl, bcl, bcl};
#pragma unroll
        for (int s = 0; s < 9; ++s) {
            int ky = s / 3, kx = s - (s / 3) * 3;
            bf16x8 Bc = *(const bf16x8*)(WcS + s * 512 + lane * 8);
#pragma unroll
            for (int mt = 0; mt < 4; ++mt) {
                int pc = (wv * 4 + mt + ky) * 18 + n16 + kx;
                bf16x8 A = *(const bf16x8*)(sAH + pc * SAH_STRIDE + quad * 8);
                accC[mt] = __builtin_amdgcn_mfma_f32_16x16x32_bf16(A, Bc, accC[mt], 0, 0, 0);
            }
        }
        float nxv[16];
#pragma unroll
        for (int mt = 0; mt < 4; ++mt)
#pragma unroll
            for (int r = 0; r < 4; ++r) {
                int k = mt * 4 + r;
                nxv[k] = (1.f - zf[k]) * hf[k] + zf[k] * tanh_fast(accC[mt][r]);
            }

        if (last) {
            int isf32 = *flagp;
            int pq = i >> 3, qq = i & 7;
#pragma unroll
            for (int mt = 0; mt < 4; ++mt) {
                long base = ((long)(b * 16 + n16) * 128 + pq * 16 + wv * 4 + mt) * 128
                            + qq * 16 + quad * 4;
                if (isf32) {
                    f32x4 v = {nxv[mt * 4], nxv[mt * 4 + 1], nxv[mt * 4 + 2], nxv[mt * 4 + 3]};
                    *(f32x4*)((float*)out + base) = v;
                } else {
                    s16x4 v = {f2bs(nxv[mt * 4]), f2bs(nxv[mt * 4 + 1]),
                               f2bs(nxv[mt * 4 + 2]), f2bs(nxv[mt * 4 + 3])};
                    *(s16x4*)((short*)out + base) = v;
                }
            }
            return;   // uniform branch: all blocks exit together
        }

        __syncthreads();   // race fix: cand-conv LDS reads done before scatter

        // ---- nx -> ch0-15 (Mnew input) AND ch16-31 (h for next iteration) ----
        float ssum = 0.f;
#pragma unroll
        for (int mt = 0; mt < 4; ++mt)
#pragma unroll
            for (int r = 0; r < 4; ++r) {
                int k = mt * 4 + r;
                ssum += nxv[k];
                int p = (wv * 4 + mt + 1) * 18 + quad * 4 + r + 1;
                short vb = f2bs(nxv[k]);
                sAH[p * SAH_STRIDE + n16] = vb;
                sAH[p * SAH_STRIDE + 16 + n16] = vb;
            }
        ssum += __shfl_xor(ssum, 16, 64);
        ssum += __shfl_xor(ssum, 32, 64);
        if (lane < 16) xred[wv * 16 + lane] = ssum;
        __syncthreads();   // nx staged + xred ready

        // ---- Mnew conv (reads ch0-15 only) -> global fp32 ----
        float bm_l = Wf[3392 + n16];
        f32x4 accM[4];
#pragma unroll
        for (int mt = 0; mt < 4; ++mt) accM[mt] = (f32x4){bm_l, bm_l, bm_l, bm_l};
#pragma unroll
        for (int sp = 0; sp < 5; ++sp) {
            bf16x8 Bf = *(const bf16x8*)(WmS + sp * 512 + lane * 8);
            int s2 = sp * 2 + (quad >> 1);
            if (s2 > 8) s2 = 8;
            int ky = s2 / 3, kx = s2 - (s2 / 3) * 3;
            int cib = (quad & 1) * 8;
#pragma unroll
            for (int mt = 0; mt < 4; ++mt) {
                int pc = (wv * 4 + mt + ky) * 18 + n16 + kx;
                bf16x8 A = *(const bf16x8*)(sAH + pc * SAH_STRIDE + cib);
                accM[mt] = __builtin_amdgcn_mfma_f32_16x16x32_bf16(A, Bf, accM[mt], 0, 0, 0);
            }
        }
        {
            float* mo = Mout + bn * 4096;
#pragma unroll
            for (int mt = 0; mt < 4; ++mt)
#pragma unroll
                for (int r = 0; r < 4; ++r) {
                    int pix = (wv * 4 + mt) * 16 + quad * 4 + r;
                    mo[pix * 16 + n16] = accM[mt][r];
                }
        }
        if (t < 64) {
            int d = t & 31;
            const float* W = (t < 32) ? Wf : Wf + 544;
            float a = (t < 32) ? Wf[512 + d] : Wf[1056 + d];
#pragma unroll
            for (int c = 0; c < 16; ++c) {
                float xc = (xred[c] + xred[16 + c] + xred[32 + c] + xred[48 + c]) * (1.f / 256.f);
                a += xc * W[c * 32 + d];
            }
            if (t < 32) qout[bn * 32 + d] = a; else kout[bn * 32 + d] = a;
        }
        __threadfence();
        cg::this_grid().sync();
    }
}

// ======================= FALLBACK ITER (R3, verified) =====================
__global__ __launch_bounds__(256, 4) void iter_kernel(
    const short* __restrict__ Xin, short* __restrict__ Xout,
    const float* __restrict__ Min, float* __restrict__ Mout,
    const float* __restrict__ qin, const float* __restrict__ kin,
    float* __restrict__ qout, float* __restrict__ kout,
    const float* __restrict__ Tpix,
    const short* __restrict__ WmS,
    const short* __restrict__ WgS,
    const short* __restrict__ WcS,
    const float* __restrict__ Wf,
    const int* __restrict__ counts, const int* __restrict__ nbrs,
    const int* __restrict__ flagp, void* __restrict__ out, int last)
{
    __shared__ __align__(16) short sAH[324 * SAH_STRIDE];
    __shared__ float evs[4];
    __shared__ float xred[64];
    int bn = blockIdx.x, b = bn >> 6, i = bn & 63;
    int t = threadIdx.x, lane = t & 63, wv = t >> 6;
    int quad = lane >> 4, n16 = lane & 15;
    int pp = ((t >> 4) + 1) * 18 + (t & 15) + 1;

    int4 nb4 = *(const int4*)(nbrs + i * 4);
    int deg = counts[i];
    int ejl[4] = {nb4.x, nb4.y, nb4.z, nb4.w};

    const short* xown = Xin + bn * 4096;

    for (int p = t; p < 324; p += 256) {
        int yy = p / 18 - 1, xx = p % 18 - 1;
        short* row = sAH + p * SAH_STRIDE;
        if ((unsigned)yy < 16u && (unsigned)xx < 16u) {
            const short* src = xown + (yy * 16 + xx) * 16;
            *(bf16x8*)(row + 16) = *(const bf16x8*)(src);
            *(bf16x8*)(row + 24) = *(const bf16x8*)(src + 8);
        } else {
            bf16x8 z = {0, 0, 0, 0, 0, 0, 0, 0};
            *(bf16x8*)(row) = z;      *(bf16x8*)(row + 8) = z;
            *(bf16x8*)(row + 16) = z; *(bf16x8*)(row + 24) = z;
        }
    }

    if (wv < deg) {
        int ej = ejl[wv];
        float h0 = (lane < 32) ? qin[bn * 32 + lane]
                               : kin[(b * 64 + ej) * 32 + (lane - 32)];
        const float* W1 = Wf + 3408;
        const float* W2 = Wf + 7568;
        float p0 = 0.f, p1 = 0.f, p2 = 0.f, p3 = 0.f;
#pragma unroll
        for (int j = 0; j < 64; j += 4) {
            p0 += __shfl(h0, j + 0, 64) * W1[(j + 0) * 64 + lane];
            p1 += __shfl(h0, j + 1, 64) * W1[(j + 1) * 64 + lane];
            p2 += __shfl(h0, j + 2, 64) * W1[(j + 2) * 64 + lane];
            p3 += __shfl(h0, j + 3, 64) * W1[(j + 3) * 64 + lane];
        }
        float a1 = fmaxf(Wf[7504 + lane] + ((p0 + p1) + (p2 + p3)), 0.f);
        p0 = p1 = p2 = p3 = 0.f;
#pragma unroll
        for (int j = 0; j < 64; j += 4) {
            p0 += __shfl(a1, j + 0, 64) * W2[(j + 0) * 64 + lane];
            p1 += __shfl(a1, j + 1, 64) * W2[(j + 1) * 64 + lane];
            p2 += __shfl(a1, j + 2, 64) * W2[(j + 2) * 64 + lane];
            p3 += __shfl(a1, j + 3, 64) * W2[(j + 3) * 64 + lane];
        }
        float a2 = fmaxf(Wf[11664 + lane] + ((p0 + p1) + (p2 + p3)), 0.f);
        float pe = a2 * Wf[11728 + lane];
#pragma unroll
        for (int off = 32; off; off >>= 1) pe += __shfl_down(pe, off, 64);
        if (lane == 0) evs[wv] = pe + Wf[11792];
    }
    __syncthreads();

    float magg[16];
#pragma unroll
    for (int c = 0; c < 16; ++c) magg[c] = 0.f;
    {
        float Tp[16];
#pragma unroll
        for (int c = 0; c < 4; ++c)
            *(f32x4*)(Tp + 4 * c) = *(const f32x4*)(Tpix + t * 16 + 4 * c);
#pragma unroll
        for (int ii = 0; ii < 4; ++ii)
            if (ii < deg) {
                const float* mp = Min + (b * 64 + ejl[ii]) * 4096 + t * 16;
                f32x4 m0 = *(const f32x4*)(mp);
                f32x4 m1 = *(const f32x4*)(mp + 4);
                f32x4 m2 = *(const f32x4*)(mp + 8);
                f32x4 m3 = *(const f32x4*)(mp + 12);
                float evv = evs[ii];
#pragma unroll
                for (int c = 0; c < 4; ++c) {
                    magg[c]      += sigm(evv * Tp[c]      + Wf[11793 + c])      * m0[c];
                    magg[c + 4]  += sigm(evv * Tp[c + 4]  + Wf[11793 + c + 4])  * m1[c];
                    magg[c + 8]  += sigm(evv * Tp[c + 8]  + Wf[11793 + c + 8])  * m2[c];
                    magg[c + 12] += sigm(evv * Tp[c + 12] + Wf[11793 + c + 12]) * m3[c];
                }
            }
    }
    {
        bf16x8 mg0, mg1;
#pragma unroll
        for (int c = 0; c < 8; ++c) { mg0[c] = f2bs(magg[c]); mg1[c] = f2bs(magg[c + 8]); }
        *(bf16x8*)(sAH + pp * SAH_STRIDE) = mg0;
        *(bf16x8*)(sAH + pp * SAH_STRIDE + 8) = mg1;
    }
    __syncthreads();

    float bz = Wf[21025 + n16], br = Wf[21025 + 16 + n16];
    f32x4 accZ[4], accR[4];
#pragma unroll
    for (int mt = 0; mt < 4; ++mt) {
        accZ[mt] = (f32x4){bz, bz, bz, bz};
        accR[mt] = (f32x4){br, br, br, br};
    }
#pragma unroll
    for (int s = 0; s < 9; ++s) {
        int ky = s / 3, kx = s - (s / 3) * 3;
        bf16x8 B0 = *(const bf16x8*)(WgS + (s * 2 + 0) * 512 + lane * 8);
        bf16x8 B1 = *(const bf16x8*)(WgS + (s * 2 + 1) * 512 + lane * 8);
#pragma unroll
        for (int mt = 0; mt < 4; ++mt) {
            int pc = (wv * 4 + mt + ky) * 18 + n16 + kx;
            bf16x8 A = *(const bf16x8*)(sAH + pc * SAH_STRIDE + quad * 8);
            accZ[mt] = __builtin_amdgcn_mfma_f32_16x16x32_bf16(A, B0, accZ[mt], 0, 0, 0);
            accR[mt] = __builtin_amdgcn_mfma_f32_16x16x32_bf16(A, B1, accR[mt], 0, 0, 0);
        }
    }
    float zf[16], hf[16], rh[16];
#pragma unroll
    for (int mt = 0; mt < 4; ++mt)
#pragma unroll
        for (int r = 0; r < 4; ++r) {
            int k = mt * 4 + r;
            int ps = (wv * 4 + mt + 1) * 18 + quad * 4 + r + 1;
            hf[k] = bs2f(sAH[ps * SAH_STRIDE + 16 + n16]);
            zf[k] = sigm(accZ[mt][r]);
            rh[k] = sigm(accR[mt][r]) * hf[k];
        }
    __syncthreads();
#pragma unroll
    for (int mt = 0; mt < 4; ++mt)
#pragma unroll
        for (int r = 0; r < 4; ++r) {
            int ps = (wv * 4 + mt + 1) * 18 + quad * 4 + r + 1;
            sAH[ps * SAH_STRIDE + 16 + n16] = f2bs(rh[mt * 4 + r]);
        }
    __syncthreads();

    float bcl = Wf[25665 + n16];
    f32x4 accC[4];
#pragma unroll
    for (int mt = 0; mt < 4; ++mt) accC[mt] = (f32x4){bcl, bcl, bcl, bcl};
#pragma unroll
    for (int s = 0; s < 9; ++s) {
        int ky = s / 3, kx = s - (s / 3) * 3;
        bf16x8 Bc = *(const bf16x8*)(WcS + s * 512 + lane * 8);
#pragma unroll
        for (int mt = 0; mt < 4; ++mt) {
            int pc = (wv * 4 + mt + ky) * 18 + n16 + kx;
            bf16x8 A = *(const bf16x8*)(sAH + pc * SAH_STRIDE + quad * 8);
            accC[mt] = __builtin_amdgcn_mfma_f32_16x16x32_bf16(A, Bc, accC[mt], 0, 0, 0);
        }
    }
    float nxv[16];
#pragma unroll
    for (int mt = 0; mt < 4; ++mt)
#pragma unroll
        for (int r = 0; r < 4; ++r) {
            int k = mt * 4 + r;
            nxv[k] = (1.f - zf[k]) * hf[k] + zf[k] * tanh_fast(accC[mt][r]);
        }

    if (last) {
        int isf32 = *flagp;
        int pq = i >> 3, qq = i & 7;
#pragma unroll
        for (int mt = 0; mt < 4; ++mt) {
            long base = ((long)(b * 16 + n16) * 128 + pq * 16 + wv * 4 + mt) * 128
                        + qq * 16 + quad * 4;
            if (isf32) {
                f32x4 v = {nxv[mt * 4], nxv[mt * 4 + 1], nxv[mt * 4 + 2], nxv[mt * 4 + 3]};
                *(f32x4*)((float*)out + base) = v;
            } else {
                s16x4 v = {f2bs(nxv[mt * 4]), f2bs(nxv[mt * 4 + 1]),
                           f2bs(nxv[mt * 4 + 2]), f2bs(nxv[mt * 4 + 3])};
                *(s16x4*)((short*)out + base) = v;
            }
        }
        return;
    }

    __syncthreads();

    float ssum = 0.f;
#pragma unroll
    for (int mt = 0; mt < 4; ++mt)
#pragma unroll
        for (int r = 0; r < 4; ++r) {
            int k = mt * 4 + r;
            ssum += nxv[k];
            int p = (wv * 4 + mt + 1) * 18 + quad * 4 + r + 1;
            sAH[p * SAH_STRIDE + n16] = f2bs(nxv[k]);
        }
    ssum += __shfl_xor(ssum, 16, 64);
    ssum += __shfl_xor(ssum, 32, 64);
    if (lane < 16) xred[wv * 16 + lane] = ssum;
    __syncthreads();

    float bm_l = Wf[3392 + n16];
    f32x4 accM[4];
#pragma unroll
    for (int mt = 0; mt < 4; ++mt) accM[mt] = (f32x4){bm_l, bm_l, bm_l, bm_l};
#pragma unroll
    for (int sp = 0; sp < 5; ++sp) {
        bf16x8 Bf = *(const bf16x8*)(WmS + sp * 512 + lane * 8);
        int s2 = sp * 2 + (quad >> 1);
        if (s2 > 8) s2 = 8;
        int ky = s2 / 3, kx = s2 - (s2 / 3) * 3;
        int cib = (quad & 1) * 8;
#pragma unroll
        for (int mt = 0; mt < 4; ++mt) {
            int pc = (wv * 4 + mt + ky) * 18 + n16 + kx;
            bf16x8 A = *(const bf16x8*)(sAH + pc * SAH_STRIDE + cib);
            accM[mt] = __builtin_amdgcn_mfma_f32_16x16x32_bf16(A, Bf, accM[mt], 0, 0, 0);
        }
    }
    {
        float* mo = Mout + bn * 4096;
#pragma unroll
        for (int mt = 0; mt < 4; ++mt)
#pragma unroll
            for (int r = 0; r < 4; ++r) {
                int pix = (wv * 4 + mt) * 16 + quad * 4 + r;
                mo[pix * 16 + n16] = accM[mt][r];
            }
    }
    {
        const short* row = sAH + pp * SAH_STRIDE;
        short* xo = Xout + bn * 4096 + t * 16;
        *(bf16x8*)(xo) = *(const bf16x8*)(row);
        *(bf16x8*)(xo + 8) = *(const bf16x8*)(row + 8);
    }
    if (t < 64) {
        int d = t & 31;
        const float* W = (t < 32) ? Wf : Wf + 544;
        float a = (t < 32) ? Wf[512 + d] : Wf[1056 + d];
#pragma unroll
        for (int c = 0; c < 16; ++c) {
            float xc = (xred[c] + xred[16 + c] + xred[32 + c] + xred[48 + c]) * (1.f / 256.f);
            a += xc * W[c * 32 + d];
        }
        if (t < 32) qout[bn * 32 + d] = a; else kout[bn * 32 + d] = a;
    }
}

extern "C" void kernel_launch(void* const* d_in, const int* in_sizes, int n_in,
                              void* d_out, int out_size, void* d_ws, size_t ws_size,
                              hipStream_t stream)
{
    const void* seed = d_in[0];
    const int* edge = (const int*)d_in[1];
    int E = in_sizes[1] / 2;  // 224

    float* ws = (float*)d_ws;
    short* Xb0 = (short*)ws;                         // 8 MB
    short* Xb1 = (short*)(ws + 2097152);             // 8 MB
    float* qv0 = ws + 4194304;                       // 32768 each
    float* kv0 = qv0 + 32768;
    float* qv1 = kv0 + 32768;
    float* kv1 = qv1 + 32768;
    float* Tpix = kv1 + 32768;                       // 4096
    float* Wf = Tpix + 4096;                         // 25681
    int* nbrs = (int*)(ws + 4355168);                // 256 ints, 16B-aligned
    int* counts = nbrs + 256;                        // 64
    int* flag = counts + 64;                         // 1
    __hip_bfloat16* swz = (__hip_bfloat16*)(ws + 4355600);  // 16384 bf16
    float* Mb0 = ws + 4363792;                       // 16 MB fp32
    float* Mb1 = ws + 8558096;                       // 16 MB fp32

    const short* WgS = (const short*)swz;
    const short* WcS = (const short*)(swz + 9216);
    const short* WmS = (const short*)(swz + 13824);

    // ---- HOST-SIDE coop viability check (pure queries, capture-safe, cached).
    // R10: prop.cooperativeLaunch REMOVED from the guard -- that flag was
    // common to all four failed guards (R6-R9), while R4 empirically proved
    // hipLaunchCooperativeKernel executes on this stack (some ROCm builds
    // report the flag as 0 regardless of actual support). Safety rests on
    // measured facts: numRegs<=128 => 4 blocks/CU => 1024-block grid exactly
    // co-resident (R4 proved runtime acceptance at this LDS/grid shape);
    // localSizeBytes==0 => no R4-style spill pathology.
    static int coop_ok = -1;
    if (coop_ok < 0) {
        int dev = 0, ncu = 0;
        hipFuncAttributes attr;
        hipError_t e1 = hipGetDevice(&dev);
        hipDeviceProp_t prop;
        hipError_t e2 = (e1 == hipSuccess) ? hipGetDeviceProperties(&prop, dev) : e1;
        hipError_t e3 = hipFuncGetAttributes(&attr, (const void*)iter4_kernel);
        if (e2 == hipSuccess) ncu = prop.multiProcessorCount;
        coop_ok = (e2 == hipSuccess && e3 == hipSuccess &&
                   attr.numRegs > 0 && attr.numRegs <= 128 &&
                   attr.localSizeBytes == 0 &&
                   (long)ncu * 4 >= (long)(Bt * Nt)) ? 1 : 0;
        (void)hipGetLastError();   // clear any sticky error from the queries
    }

    // Setup is identical on both paths.
    setup_kernel<<<Bt * Nt, 256, 0, stream>>>(
        seed,
        d_in[2], d_in[3], d_in[4], d_in[5], d_in[6], d_in[7], d_in[8], d_in[9],
        d_in[10], d_in[11], d_in[12], d_in[13], d_in[14], d_in[15], d_in[16],
        d_in[17], d_in[18], d_in[19],
        edge, E, Wf, Tpix, counts, nbrs, swz, Xb0, qv0, kv0, Mb0, flag);

    if (coop_ok == 1) {
        const short* Xin = Xb0;
        void* outp = d_out;
        void* kargs[] = {
            (void*)&Xin,
            (void*)&Mb0, (void*)&Mb1,
            (void*)&qv0, (void*)&kv0, (void*)&qv1, (void*)&kv1,
            (void*)&Tpix, (void*)&WmS, (void*)&WgS, (void*)&WcS, (void*)&Wf,
            (void*)&counts, (void*)&nbrs, (void*)&flag, (void*)&outp
        };
        hipError_t rc = hipLaunchCooperativeKernel(
            (const void*)iter4_kernel, dim3(Bt * Nt), dim3(256), kargs, 0, stream);
        if (rc == hipSuccess) return;
        (void)hipGetLastError();
        coop_ok = 0;   // fall through to the verified dispatch path
    }

    short* Xs[2] = {Xb0, Xb1};
    float* Ms[2] = {Mb0, Mb1};
    float* qs[2] = {qv0, qv1};
    float* ks[2] = {kv0, kv1};
    for (int it = 0; it < KITERt; ++it) {
        int in = it & 1, on = in ^ 1;
        int last = (it == KITERt - 1);
        iter_kernel<<<Bt * Nt, 256, 0, stream>>>(
            Xs[in], Xs[on], Ms[in], Ms[on], qs[in], ks[in], qs[on], ks[on],
            Tpix, WmS, WgS, WcS, Wf, counts, nbrs, flag, d_out, last);
    }
}

// Round 11
// 224.817 us; speedup vs baseline: 1.0067x; 1.0067x over previous
//
#include <hip/hip_runtime.h>
#include <hip/hip_bf16.h>
#include <hip/hip_cooperative_groups.h>

namespace cg = cooperative_groups;

#define Bt 16
#define Ct 16
#define Nt 64
#define KITERt 4

// ---------- fp32 weight block offsets (floats) ----------
// wq@0(512) bq@512(32) wk@544(512) bk@1056(32) wm@1088(2304) bm@3392(16)
// w1@3408(4096) b1@7504(64) w2@7568(4096) b2@11664(64) wo@11728(64) bo@11792(1)
// gb@11793(16) wg@11809(9216) bg@21025(32) wc@21057(4608) bc@25665(16)
#define WF_TOTAL 25681
#define SWZ_TOTAL 16384
#define SETUP_IDX (WF_TOTAL + 4096 + Nt + SWZ_TOTAL)
#define SAH_STRIDE 40

typedef __attribute__((ext_vector_type(8))) short bf16x8;
typedef __attribute__((ext_vector_type(4))) short s16x4;
typedef __attribute__((ext_vector_type(4))) float f32x4;

__device__ inline short f2bs(float f) {
    __hip_bfloat16 h = __float2bfloat16(f);
    short s; __builtin_memcpy(&s, &h, 2); return s;
}
__device__ inline float bs2f(short s) {
    __hip_bfloat16 h; __builtin_memcpy(&h, &s, 2);
    return __bfloat162float(h);
}
__device__ inline float loadf(const void* p, int i, int isf32) {
    return isf32 ? ((const float*)p)[i]
                 : __bfloat162float(((const __hip_bfloat16*)p)[i]);
}
__device__ inline float sigm(float x) {
    return __builtin_amdgcn_rcpf(1.f + __expf(-x));
}
__device__ inline float tanh_fast(float x) {
    float e = __expf(2.f * x);
    return 1.f - 2.f * __builtin_amdgcn_rcpf(e + 1.f);
}

// ======================= SETUP (R3, verified; normal dispatch) ============
__global__ __launch_bounds__(256) void setup_kernel(
    const void* __restrict__ seed,
    const void* __restrict__ wq, const void* __restrict__ bq,
    const void* __restrict__ wk, const void* __restrict__ bk,
    const void* __restrict__ wm, const void* __restrict__ bm,
    const void* __restrict__ w1, const void* __restrict__ b1,
    const void* __restrict__ w2, const void* __restrict__ b2,
    const void* __restrict__ wo, const void* __restrict__ bo,
    const void* __restrict__ gw, const void* __restrict__ gb,
    const void* __restrict__ wg, const void* __restrict__ bg,
    const void* __restrict__ wc, const void* __restrict__ bc,
    const int* __restrict__ edge, int E,
    float* __restrict__ Wf, float* __restrict__ Tpix,
    int* __restrict__ counts, int* __restrict__ nbrs,
    __hip_bfloat16* __restrict__ swz,
    short* __restrict__ Xb, float* __restrict__ qv0, float* __restrict__ kv0,
    float* __restrict__ M0,
    int* __restrict__ flag)
{
    __shared__ float sred[4];
    __shared__ int sflag;
    __shared__ float xred[64];
    __shared__ int snb[256];
    __shared__ __align__(16) short sM[324 * SAH_STRIDE];
    int bn = blockIdx.x, t = threadIdx.x;
    int lane = t & 63, wv = t >> 6;
    int quad = lane >> 4, n16 = lane & 15;

    {
        float v = fabsf(__bfloat162float(((const __hip_bfloat16*)seed)[t]));
        if (!(v <= 1e30f)) v = 1e30f;
#pragma unroll
        for (int off = 1; off < 64; off <<= 1) v = fmaxf(v, __shfl_xor(v, off, 64));
        if (lane == 0) sred[wv] = v;
        __syncthreads();
        if (t == 0) {
            float m = fmaxf(fmaxf(sred[0], sred[1]), fmaxf(sred[2], sred[3]));
            sflag = (m > 1e10f) ? 1 : 0;
            if (bn == 0) *flag = sflag;
        }
        __syncthreads();
    }
    int isf32 = sflag;

    if (bn == 0) {
        snb[t] = 0;
        __syncthreads();
        for (int e = t; e < E; e += 256) {
            int ei = edge[2 * e], ej = edge[2 * e + 1];
            int d = ej - ei;
            int slot = (d == 1) ? 0 : (d == 8) ? 1 : (d == -1) ? 2 : 3;
            snb[ei * 4 + slot] = ej + 1;
        }
        __syncthreads();
        if (t < 64) {
            int dcount = 0;
            int outv[4] = {0, 0, 0, 0};
#pragma unroll
            for (int s = 0; s < 4; ++s) {
                int v = snb[t * 4 + s];
                if (v) outv[dcount++] = v - 1;
            }
            counts[t] = dcount;
#pragma unroll
            for (int s = 0; s < 4; ++s) nbrs[t * 4 + s] = outv[s];
        }
    }

    int idx = bn * 256 + t;
    if (idx < WF_TOTAL) {
        int i = idx;
        const void* base;
        if (i < 512) base = wq;
        else if ((i -= 512) < 32) base = bq;
        else if ((i -= 32) < 512) base = wk;
        else if ((i -= 512) < 32) base = bk;
        else if ((i -= 32) < 2304) base = wm;
        else if ((i -= 2304) < 16) base = bm;
        else if ((i -= 16) < 4096) base = w1;
        else if ((i -= 4096) < 64) base = b1;
        else if ((i -= 64) < 4096) base = w2;
        else if ((i -= 4096) < 64) base = b2;
        else if ((i -= 64) < 64) base = wo;
        else if ((i -= 64) < 1) base = bo;
        else if ((i -= 1) < 16) base = gb;
        else if ((i -= 16) < 9216) base = wg;
        else if ((i -= 9216) < 32) base = bg;
        else if ((i -= 32) < 4608) base = wc;
        else { i -= 4608; base = bc; }
        Wf[idx] = loadf(base, i, isf32);
    } else if (idx < WF_TOTAL + 4096) {
        int j = idx - WF_TOTAL;
        int pix = j >> 4, ch = j & 15;
        int y = pix >> 4, x = pix & 15;
        float s = 0.f;
        for (int ky = 0; ky < 3; ++ky)
            for (int kx = 0; kx < 3; ++kx) {
                int yy = y + ky - 1, xx = x + kx - 1;
                if (yy >= 0 && yy < 16 && xx >= 0 && xx < 16)
                    s += loadf(gw, ch * 9 + ky * 3 + kx, isf32);
            }
        Tpix[j] = s;
    } else if (idx >= WF_TOTAL + 4096 + Nt && idx < SETUP_IDX) {
        int j = idx - (WF_TOTAL + 4096 + Nt);
        float val;
        if (j < 9216) {
            int sn = j >> 9, rem = j & 511;
            int ln = rem >> 3, jj = rem & 7;
            int s = sn >> 1, nt = sn & 1;
            int ci = (ln >> 4) * 8 + jj;
            int co = nt * 16 + (ln & 15);
            val = loadf(wg, co * 288 + ci * 9 + s, isf32);
        } else if (j < 9216 + 4608) {
            int j1 = j - 9216;
            int s = j1 >> 9, rem = j1 & 511;
            int ln = rem >> 3, jj = rem & 7;
            int ci = (ln >> 4) * 8 + jj;
            int co = ln & 15;
            val = loadf(wc, co * 288 + ci * 9 + s, isf32);
        } else {
            int j2 = j - 13824;
            int sp = j2 >> 9, rem = j2 & 511;
            int ln = rem >> 3, jj = rem & 7;
            int k = (ln >> 4) * 8 + jj;
            int s = sp * 2 + (k >> 4);
            int ci = k & 15;
            int co = ln & 15;
            val = (s <= 8) ? loadf(wm, co * 144 + ci * 9 + s, isf32) : 0.f;
        }
        swz[j] = __float2bfloat16(val);
    }

    {
        int b = bn >> 6, n = bn & 63;
        int pq = n >> 3, qq = n & 7;
        int y = t >> 4, x = t & 15;
        float v[16];
#pragma unroll
        for (int c = 0; c < 16; ++c)
            v[c] = loadf(seed, ((b * 16 + c) * 128 + pq * 16 + y) * 128 + qq * 16 + x, isf32);
        bf16x8 o0, o1;
#pragma unroll
        for (int c = 0; c < 8; ++c) { o0[c] = f2bs(v[c]); o1[c] = f2bs(v[8 + c]); }
        short* xo = Xb + bn * 4096;
        *(bf16x8*)(xo + t * 16) = o0;
        *(bf16x8*)(xo + t * 16 + 8) = o1;

        for (int p = t; p < 324; p += 256) {
            int yy = p / 18 - 1, xx = p % 18 - 1;
            if (!((unsigned)yy < 16u && (unsigned)xx < 16u)) {
                bf16x8 z = {0, 0, 0, 0, 0, 0, 0, 0};
                *(bf16x8*)(sM + p * SAH_STRIDE) = z;
                *(bf16x8*)(sM + p * SAH_STRIDE + 8) = z;
            }
        }
        int pp = ((t >> 4) + 1) * 18 + (t & 15) + 1;
        *(bf16x8*)(sM + pp * SAH_STRIDE) = o0;
        *(bf16x8*)(sM + pp * SAH_STRIDE + 8) = o1;

#pragma unroll
        for (int c = 0; c < 16; ++c) {
            float s = v[c];
#pragma unroll
            for (int off = 1; off < 64; off <<= 1) s += __shfl_xor(s, off, 64);
            if (lane == c) xred[wv * 16 + c] = s;
        }
        __syncthreads();
        if (t < 64) {
            int d = t & 31;
            float a = (t < 32) ? loadf(bq, d, isf32) : loadf(bk, d, isf32);
#pragma unroll
            for (int c = 0; c < 16; ++c) {
                float xm = (xred[c] + xred[16 + c] + xred[32 + c] + xred[48 + c]) * (1.f / 256.f);
                a += xm * ((t < 32) ? loadf(wq, c * 32 + d, isf32)
                                    : loadf(wk, c * 32 + d, isf32));
            }
            if (t < 32) qv0[bn * 32 + d] = a; else kv0[bn * 32 + d] = a;
        }

        float bm_l = loadf(bm, n16, isf32);
        f32x4 accM[4];
#pragma unroll
        for (int mt = 0; mt < 4; ++mt) accM[mt] = (f32x4){bm_l, bm_l, bm_l, bm_l};
#pragma unroll
        for (int sp = 0; sp < 5; ++sp) {
            int s2 = sp * 2 + (quad >> 1);
            int valid = (s2 <= 8);
            int s2c = valid ? s2 : 8;
            int ky = s2c / 3, kx = s2c - ky * 3;
            bf16x8 Bf;
#pragma unroll
            for (int j = 0; j < 8; ++j) {
                short bv = 0;
                if (valid) bv = f2bs(loadf(wm, n16 * 144 + ((quad & 1) * 8 + j) * 9 + s2, isf32));
                Bf[j] = bv;
            }
            int cib = (quad & 1) * 8;
#pragma unroll
            for (int mt = 0; mt < 4; ++mt) {
                int pc = (wv * 4 + mt + ky) * 18 + n16 + kx;
                bf16x8 A = *(const bf16x8*)(sM + pc * SAH_STRIDE + cib);
                accM[mt] = __builtin_amdgcn_mfma_f32_16x16x32_bf16(A, Bf, accM[mt], 0, 0, 0);
            }
        }
        float* mo = M0 + bn * 4096;
#pragma unroll
        for (int mt = 0; mt < 4; ++mt)
#pragma unroll
            for (int r = 0; r < 4; ++r) {
                int pix = (wv * 4 + mt) * 16 + quad * 4 + r;
                mo[pix * 16 + n16] = accM[mt][r];
            }
    }
}

// ============== COOPERATIVE 4-ITERATION KERNEL (no setup code) ============
// R11 guard rebuild: (1) co-residency verified by the OCCUPANCY API (>=4
// blocks/CU) -- with (256,4) pinning the compiler is forced to fit, so this
// should report 4+; (2) localSizeBytes <= 64 tolerates benign allocator
// scratch crumbs (R10's zero-tolerance check may have vetoed a config whose
// baseline twin, R3's iter_kernel, performs perfectly). numRegs and the
// unreliable prop.cooperativeLaunch flag are gone. R4 proved the runtime
// ACCEPTS coop launches at this exact grid/LDS shape.
__global__ __launch_bounds__(256, 4)
void iter4_kernel(
    const short* __restrict__ Xin,
    float* __restrict__ Mb0, float* __restrict__ Mb1,
    float* __restrict__ qv0, float* __restrict__ kv0,
    float* __restrict__ qv1, float* __restrict__ kv1,
    const float* __restrict__ Tpix,
    const short* __restrict__ WmS,
    const short* __restrict__ WgS,
    const short* __restrict__ WcS,
    const float* __restrict__ Wf,
    const int* __restrict__ counts, const int* __restrict__ nbrs,
    const int* __restrict__ flagp, void* __restrict__ out)
{
    __shared__ __align__(16) short sAH[324 * SAH_STRIDE];  // ch0-15 Magg/nx, ch16-31 h/rh
    __shared__ float evs[4];
    __shared__ float xred[64];
    int bn = blockIdx.x, b = bn >> 6, i = bn & 63;
    int t = threadIdx.x, lane = t & 63, wv = t >> 6;
    int quad = lane >> 4, n16 = lane & 15;
    int pp = ((t >> 4) + 1) * 18 + (t & 15) + 1;

    int4 nb4 = *(const int4*)(nbrs + i * 4);
    int deg = counts[i];
    int ejl[4] = {nb4.x, nb4.y, nb4.z, nb4.w};

    // ---- phase A (ONCE): stage own h into ch16-31; zero all borders ----
    const short* xown = Xin + bn * 4096;
    for (int p = t; p < 324; p += 256) {
        int yy = p / 18 - 1, xx = p % 18 - 1;
        short* row = sAH + p * SAH_STRIDE;
        if ((unsigned)yy < 16u && (unsigned)xx < 16u) {
            const short* src = xown + (yy * 16 + xx) * 16;
            *(bf16x8*)(row + 16) = *(const bf16x8*)(src);
            *(bf16x8*)(row + 24) = *(const bf16x8*)(src + 8);
        } else {
            bf16x8 z = {0, 0, 0, 0, 0, 0, 0, 0};
            *(bf16x8*)(row) = z;      *(bf16x8*)(row + 8) = z;
            *(bf16x8*)(row + 16) = z; *(bf16x8*)(row + 24) = z;
        }
    }

#pragma unroll 1
    for (int it = 0; it < KITERt; ++it) {
        const float* Min  = (it & 1) ? Mb1 : Mb0;
        float*       Mout = (it & 1) ? Mb0 : Mb1;
        const float* qin  = (it & 1) ? qv1 : qv0;
        const float* kin  = (it & 1) ? kv1 : kv0;
        float*       qout = (it & 1) ? qv0 : qv1;
        float*       kout = (it & 1) ? kv0 : kv1;
        int last = (it == KITERt - 1);

        // ---- phase B: edge MLP ----
        if (wv < deg) {
            int ej = ejl[wv];
            float h0 = (lane < 32) ? qin[bn * 32 + lane]
                                   : kin[(b * 64 + ej) * 32 + (lane - 32)];
            const float* W1 = Wf + 3408;
            const float* W2 = Wf + 7568;
            float p0 = 0.f, p1 = 0.f, p2 = 0.f, p3 = 0.f;
#pragma unroll
            for (int j = 0; j < 64; j += 4) {
                p0 += __shfl(h0, j + 0, 64) * W1[(j + 0) * 64 + lane];
                p1 += __shfl(h0, j + 1, 64) * W1[(j + 1) * 64 + lane];
                p2 += __shfl(h0, j + 2, 64) * W1[(j + 2) * 64 + lane];
                p3 += __shfl(h0, j + 3, 64) * W1[(j + 3) * 64 + lane];
            }
            float a1 = fmaxf(Wf[7504 + lane] + ((p0 + p1) + (p2 + p3)), 0.f);
            p0 = p1 = p2 = p3 = 0.f;
#pragma unroll
            for (int j = 0; j < 64; j += 4) {
                p0 += __shfl(a1, j + 0, 64) * W2[(j + 0) * 64 + lane];
                p1 += __shfl(a1, j + 1, 64) * W2[(j + 1) * 64 + lane];
                p2 += __shfl(a1, j + 2, 64) * W2[(j + 2) * 64 + lane];
                p3 += __shfl(a1, j + 3, 64) * W2[(j + 3) * 64 + lane];
            }
            float a2 = fmaxf(Wf[11664 + lane] + ((p0 + p1) + (p2 + p3)), 0.f);
            float pe = a2 * Wf[11728 + lane];
#pragma unroll
            for (int off = 32; off; off >>= 1) pe += __shfl_down(pe, off, 64);
            if (lane == 0) evs[wv] = pe + Wf[11792];
        }
        __syncthreads();

        // ---- phase C: gated aggregation of neighbor M ----
        float magg[16];
#pragma unroll
        for (int c = 0; c < 16; ++c) magg[c] = 0.f;
        {
            float Tp[16];
#pragma unroll
            for (int c = 0; c < 4; ++c)
                *(f32x4*)(Tp + 4 * c) = *(const f32x4*)(Tpix + t * 16 + 4 * c);
#pragma unroll 1
            for (int ii = 0; ii < 4; ++ii)
                if (ii < deg) {
                    const float* mp = Min + (b * 64 + ejl[ii]) * 4096 + t * 16;
                    f32x4 m0 = *(const f32x4*)(mp);
                    f32x4 m1 = *(const f32x4*)(mp + 4);
                    f32x4 m2 = *(const f32x4*)(mp + 8);
                    f32x4 m3 = *(const f32x4*)(mp + 12);
                    float evv = evs[ii];
#pragma unroll
                    for (int c = 0; c < 4; ++c) {
                        magg[c]      += sigm(evv * Tp[c]      + Wf[11793 + c])      * m0[c];
                        magg[c + 4]  += sigm(evv * Tp[c + 4]  + Wf[11793 + c + 4])  * m1[c];
                        magg[c + 8]  += sigm(evv * Tp[c + 8]  + Wf[11793 + c + 8])  * m2[c];
                        magg[c + 12] += sigm(evv * Tp[c + 12] + Wf[11793 + c + 12]) * m3[c];
                    }
                }
        }
        {
            bf16x8 mg0, mg1;
#pragma unroll
            for (int c = 0; c < 8; ++c) { mg0[c] = f2bs(magg[c]); mg1[c] = f2bs(magg[c + 8]); }
            *(bf16x8*)(sAH + pp * SAH_STRIDE) = mg0;
            *(bf16x8*)(sAH + pp * SAH_STRIDE + 8) = mg1;
        }
        __syncthreads();

        // ---- zr conv ----
        float bz = Wf[21025 + n16], br = Wf[21025 + 16 + n16];
        f32x4 accZ[4], accR[4];
#pragma unroll
        for (int mt = 0; mt < 4; ++mt) {
            accZ[mt] = (f32x4){bz, bz, bz, bz};
            accR[mt] = (f32x4){br, br, br, br};
        }
#pragma unroll
        for (int s = 0; s < 9; ++s) {
            int ky = s / 3, kx = s - (s / 3) * 3;
            bf16x8 B0 = *(const bf16x8*)(WgS + (s * 2 + 0) * 512 + lane * 8);
            bf16x8 B1 = *(const bf16x8*)(WgS + (s * 2 + 1) * 512 + lane * 8);
#pragma unroll
            for (int mt = 0; mt < 4; ++mt) {
                int pc = (wv * 4 + mt + ky) * 18 + n16 + kx;
                bf16x8 A = *(const bf16x8*)(sAH + pc * SAH_STRIDE + quad * 8);
                accZ[mt] = __builtin_amdgcn_mfma_f32_16x16x32_bf16(A, B0, accZ[mt], 0, 0, 0);
                accR[mt] = __builtin_amdgcn_mfma_f32_16x16x32_bf16(A, B1, accR[mt], 0, 0, 0);
            }
        }
        float zf[16], hf[16], rh[16];
#pragma unroll
        for (int mt = 0; mt < 4; ++mt)
#pragma unroll
            for (int r = 0; r < 4; ++r) {
                int k = mt * 4 + r;
                int ps = (wv * 4 + mt + 1) * 18 + quad * 4 + r + 1;
                hf[k] = bs2f(sAH[ps * SAH_STRIDE + 16 + n16]);
                zf[k] = sigm(accZ[mt][r]);
                rh[k] = sigm(accR[mt][r]) * hf[k];
            }
        __syncthreads();
#pragma unroll
        for (int mt = 0; mt < 4; ++mt)
#pragma unroll
            for (int r = 0; r < 4; ++r) {
                int ps = (wv * 4 + mt + 1) * 18 + quad * 4 + r + 1;
                sAH[ps * SAH_STRIDE + 16 + n16] = f2bs(rh[mt * 4 + r]);
            }
        __syncthreads();

        // ---- cand conv ----
        float bcl = Wf[25665 + n16];
        f32x4 accC[4];
#pragma unroll
        for (int mt = 0; mt < 4; ++mt) accC[mt] = (f32x4){bcl, bcl, bcl, bcl};
#pragma unroll
        for (int s = 0; s < 9; ++s) {
            int ky = s / 3, kx = s - (s / 3) * 3;
            bf16x8 Bc = *(const bf16x8*)(WcS + s * 512 + lane * 8);
#pragma unroll
            for (int mt = 0; mt < 4; ++mt) {
                int pc = (wv * 4 + mt + ky) * 18 + n16 + kx;
                bf16x8 A = *(const bf16x8*)(sAH + pc * SAH_STRIDE + quad * 8);
                accC[mt] = __builtin_amdgcn_mfma_f32_16x16x32_bf16(A, Bc, accC[mt], 0, 0, 0);
            }
        }
        float nxv[16];
#pragma unroll
        for (int mt = 0; mt < 4; ++mt)
#pragma unroll
            for (int r = 0; r < 4; ++r) {
                int k = mt * 4 + r;
                nxv[k] = (1.f - zf[k]) * hf[k] + zf[k] * tanh_fast(accC[mt][r]);
            }

        if (last) {
            int isf32 = *flagp;
            int pq = i >> 3, qq = i & 7;
#pragma unroll
            for (int mt = 0; mt < 4; ++mt) {
                long base = ((long)(b * 16 + n16) * 128 + pq * 16 + wv * 4 + mt) * 128
                            + qq * 16 + quad * 4;
                if (isf32) {
                    f32x4 v = {nxv[mt * 4], nxv[mt * 4 + 1], nxv[mt * 4 + 2], nxv[mt * 4 + 3]};
                    *(f32x4*)((float*)out + base) = v;
                } else {
                    s16x4 v = {f2bs(nxv[mt * 4]), f2bs(nxv[mt * 4 + 1]),
                               f2bs(nxv[mt * 4 + 2]), f2bs(nxv[mt * 4 + 3])};
                    *(s16x4*)((short*)out + base) = v;
                }
            }
            return;   // uniform branch: all blocks exit together
        }

        __syncthreads();   // race fix: cand-conv LDS reads done before scatter

        // ---- nx -> ch0-15 (Mnew input) AND ch16-31 (h for next iteration) ----
        float ssum = 0.f;
#pragma unroll
        for (int mt = 0; mt < 4; ++mt)
#pragma unroll
            for (int r = 0; r < 4; ++r) {
                int k = mt * 4 + r;
                ssum += nxv[k];
                int p = (wv * 4 + mt + 1) * 18 + quad * 4 + r + 1;
                short vb = f2bs(nxv[k]);
                sAH[p * SAH_STRIDE + n16] = vb;
                sAH[p * SAH_STRIDE + 16 + n16] = vb;
            }
        ssum += __shfl_xor(ssum, 16, 64);
        ssum += __shfl_xor(ssum, 32, 64);
        if (lane < 16) xred[wv * 16 + lane] = ssum;
        __syncthreads();   // nx staged + xred ready

        // ---- Mnew conv (reads ch0-15 only) -> global fp32 ----
        float bm_l = Wf[3392 + n16];
        f32x4 accM[4];
#pragma unroll
        for (int mt = 0; mt < 4; ++mt) accM[mt] = (f32x4){bm_l, bm_l, bm_l, bm_l};
#pragma unroll
        for (int sp = 0; sp < 5; ++sp) {
            bf16x8 Bf = *(const bf16x8*)(WmS + sp * 512 + lane * 8);
            int s2 = sp * 2 + (quad >> 1);
            if (s2 > 8) s2 = 8;
            int ky = s2 / 3, kx = s2 - (s2 / 3) * 3;
            int cib = (quad & 1) * 8;
#pragma unroll
            for (int mt = 0; mt < 4; ++mt) {
                int pc = (wv * 4 + mt + ky) * 18 + n16 + kx;
                bf16x8 A = *(const bf16x8*)(sAH + pc * SAH_STRIDE + cib);
                accM[mt] = __builtin_amdgcn_mfma_f32_16x16x32_bf16(A, Bf, accM[mt], 0, 0, 0);
            }
        }
        {
            float* mo = Mout + bn * 4096;
#pragma unroll
            for (int mt = 0; mt < 4; ++mt)
#pragma unroll
                for (int r = 0; r < 4; ++r) {
                    int pix = (wv * 4 + mt) * 16 + quad * 4 + r;
                    mo[pix * 16 + n16] = accM[mt][r];
                }
        }
        if (t < 64) {
            int d = t & 31;
            const float* W = (t < 32) ? Wf : Wf + 544;
            float a = (t < 32) ? Wf[512 + d] : Wf[1056 + d];
#pragma unroll
            for (int c = 0; c < 16; ++c) {
                float xc = (xred[c] + xred[16 + c] + xred[32 + c] + xred[48 + c]) * (1.f / 256.f);
                a += xc * W[c * 32 + d];
            }
            if (t < 32) qout[bn * 32 + d] = a; else kout[bn * 32 + d] = a;
        }
        __threadfence();
        cg::this_grid().sync();
    }
}

// ======================= FALLBACK ITER (R3, verified) =====================
__global__ __launch_bounds__(256, 4) void iter_kernel(
    const short* __restrict__ Xin, short* __restrict__ Xout,
    const float* __restrict__ Min, float* __restrict__ Mout,
    const float* __restrict__ qin, const float* __restrict__ kin,
    float* __restrict__ qout, float* __restrict__ kout,
    const float* __restrict__ Tpix,
    const short* __restrict__ WmS,
    const short* __restrict__ WgS,
    const short* __restrict__ WcS,
    const float* __restrict__ Wf,
    const int* __restrict__ counts, const int* __restrict__ nbrs,
    const int* __restrict__ flagp, void* __restrict__ out, int last)
{
    __shared__ __align__(16) short sAH[324 * SAH_STRIDE];
    __shared__ float evs[4];
    __shared__ float xred[64];
    int bn = blockIdx.x, b = bn >> 6, i = bn & 63;
    int t = threadIdx.x, lane = t & 63, wv = t >> 6;
    int quad = lane >> 4, n16 = lane & 15;
    int pp = ((t >> 4) + 1) * 18 + (t & 15) + 1;

    int4 nb4 = *(const int4*)(nbrs + i * 4);
    int deg = counts[i];
    int ejl[4] = {nb4.x, nb4.y, nb4.z, nb4.w};

    const short* xown = Xin + bn * 4096;

    for (int p = t; p < 324; p += 256) {
        int yy = p / 18 - 1, xx = p % 18 - 1;
        short* row = sAH + p * SAH_STRIDE;
        if ((unsigned)yy < 16u && (unsigned)xx < 16u) {
            const short* src = xown + (yy * 16 + xx) * 16;
            *(bf16x8*)(row + 16) = *(const bf16x8*)(src);
            *(bf16x8*)(row + 24) = *(const bf16x8*)(src + 8);
        } else {
            bf16x8 z = {0, 0, 0, 0, 0, 0, 0, 0};
            *(bf16x8*)(row) = z;      *(bf16x8*)(row + 8) = z;
            *(bf16x8*)(row + 16) = z; *(bf16x8*)(row + 24) = z;
        }
    }

    if (wv < deg) {
        int ej = ejl[wv];
        float h0 = (lane < 32) ? qin[bn * 32 + lane]
                               : kin[(b * 64 + ej) * 32 + (lane - 32)];
        const float* W1 = Wf + 3408;
        const float* W2 = Wf + 7568;
        float p0 = 0.f, p1 = 0.f, p2 = 0.f, p3 = 0.f;
#pragma unroll
        for (int j = 0; j < 64; j += 4) {
            p0 += __shfl(h0, j + 0, 64) * W1[(j + 0) * 64 + lane];
            p1 += __shfl(h0, j + 1, 64) * W1[(j + 1) * 64 + lane];
            p2 += __shfl(h0, j + 2, 64) * W1[(j + 2) * 64 + lane];
            p3 += __shfl(h0, j + 3, 64) * W1[(j + 3) * 64 + lane];
        }
        float a1 = fmaxf(Wf[7504 + lane] + ((p0 + p1) + (p2 + p3)), 0.f);
        p0 = p1 = p2 = p3 = 0.f;
#pragma unroll
        for (int j = 0; j < 64; j += 4) {
            p0 += __shfl(a1, j + 0, 64) * W2[(j + 0) * 64 + lane];
            p1 += __shfl(a1, j + 1, 64) * W2[(j + 1) * 64 + lane];
            p2 += __shfl(a1, j + 2, 64) * W2[(j + 2) * 64 + lane];
            p3 += __shfl(a1, j + 3, 64) * W2[(j + 3) * 64 + lane];
        }
        float a2 = fmaxf(Wf[11664 + lane] + ((p0 + p1) + (p2 + p3)), 0.f);
        float pe = a2 * Wf[11728 + lane];
#pragma unroll
        for (int off = 32; off; off >>= 1) pe += __shfl_down(pe, off, 64);
        if (lane == 0) evs[wv] = pe + Wf[11792];
    }
    __syncthreads();

    float magg[16];
#pragma unroll
    for (int c = 0; c < 16; ++c) magg[c] = 0.f;
    {
        float Tp[16];
#pragma unroll
        for (int c = 0; c < 4; ++c)
            *(f32x4*)(Tp + 4 * c) = *(const f32x4*)(Tpix + t * 16 + 4 * c);
#pragma unroll
        for (int ii = 0; ii < 4; ++ii)
            if (ii < deg) {
                const float* mp = Min + (b * 64 + ejl[ii]) * 4096 + t * 16;
                f32x4 m0 = *(const f32x4*)(mp);
                f32x4 m1 = *(const f32x4*)(mp + 4);
                f32x4 m2 = *(const f32x4*)(mp + 8);
                f32x4 m3 = *(const f32x4*)(mp + 12);
                float evv = evs[ii];
#pragma unroll
                for (int c = 0; c < 4; ++c) {
                    magg[c]      += sigm(evv * Tp[c]      + Wf[11793 + c])      * m0[c];
                    magg[c + 4]  += sigm(evv * Tp[c + 4]  + Wf[11793 + c + 4])  * m1[c];
                    magg[c + 8]  += sigm(evv * Tp[c + 8]  + Wf[11793 + c + 8])  * m2[c];
                    magg[c + 12] += sigm(evv * Tp[c + 12] + Wf[11793 + c + 12]) * m3[c];
                }
            }
    }
    {
        bf16x8 mg0, mg1;
#pragma unroll
        for (int c = 0; c < 8; ++c) { mg0[c] = f2bs(magg[c]); mg1[c] = f2bs(magg[c + 8]); }
        *(bf16x8*)(sAH + pp * SAH_STRIDE) = mg0;
        *(bf16x8*)(sAH + pp * SAH_STRIDE + 8) = mg1;
    }
    __syncthreads();

    float bz = Wf[21025 + n16], br = Wf[21025 + 16 + n16];
    f32x4 accZ[4], accR[4];
#pragma unroll
    for (int mt = 0; mt < 4; ++mt) {
        accZ[mt] = (f32x4){bz, bz, bz, bz};
        accR[mt] = (f32x4){br, br, br, br};
    }
#pragma unroll
    for (int s = 0; s < 9; ++s) {
        int ky = s / 3, kx = s - (s / 3) * 3;
        bf16x8 B0 = *(const bf16x8*)(WgS + (s * 2 + 0) * 512 + lane * 8);
        bf16x8 B1 = *(const bf16x8*)(WgS + (s * 2 + 1) * 512 + lane * 8);
#pragma unroll
        for (int mt = 0; mt < 4; ++mt) {
            int pc = (wv * 4 + mt + ky) * 18 + n16 + kx;
            bf16x8 A = *(const bf16x8*)(sAH + pc * SAH_STRIDE + quad * 8);
            accZ[mt] = __builtin_amdgcn_mfma_f32_16x16x32_bf16(A, B0, accZ[mt], 0, 0, 0);
            accR[mt] = __builtin_amdgcn_mfma_f32_16x16x32_bf16(A, B1, accR[mt], 0, 0, 0);
        }
    }
    float zf[16], hf[16], rh[16];
#pragma unroll
    for (int mt = 0; mt < 4; ++mt)
#pragma unroll
        for (int r = 0; r < 4; ++r) {
            int k = mt * 4 + r;
            int ps = (wv * 4 + mt + 1) * 18 + quad * 4 + r + 1;
            hf[k] = bs2f(sAH[ps * SAH_STRIDE + 16 + n16]);
            zf[k] = sigm(accZ[mt][r]);
            rh[k] = sigm(accR[mt][r]) * hf[k];
        }
    __syncthreads();
#pragma unroll
    for (int mt = 0; mt < 4; ++mt)
#pragma unroll
        for (int r = 0; r < 4; ++r) {
            int ps = (wv * 4 + mt + 1) * 18 + quad * 4 + r + 1;
            sAH[ps * SAH_STRIDE + 16 + n16] = f2bs(rh[mt * 4 + r]);
        }
    __syncthreads();

    float bcl = Wf[25665 + n16];
    f32x4 accC[4];
#pragma unroll
    for (int mt = 0; mt < 4; ++mt) accC[mt] = (f32x4){bcl, bcl, bcl, bcl};
#pragma unroll
    for (int s = 0; s < 9; ++s) {
        int ky = s / 3, kx = s - (s / 3) * 3;
        bf16x8 Bc = *(const bf16x8*)(WcS + s * 512 + lane * 8);
#pragma unroll
        for (int mt = 0; mt < 4; ++mt) {
            int pc = (wv * 4 + mt + ky) * 18 + n16 + kx;
            bf16x8 A = *(const bf16x8*)(sAH + pc * SAH_STRIDE + quad * 8);
            accC[mt] = __builtin_amdgcn_mfma_f32_16x16x32_bf16(A, Bc, accC[mt], 0, 0, 0);
        }
    }
    float nxv[16];
#pragma unroll
    for (int mt = 0; mt < 4; ++mt)
#pragma unroll
        for (int r = 0; r < 4; ++r) {
            int k = mt * 4 + r;
            nxv[k] = (1.f - zf[k]) * hf[k] + zf[k] * tanh_fast(accC[mt][r]);
        }

    if (last) {
        int isf32 = *flagp;
        int pq = i >> 3, qq = i & 7;
#pragma unroll
        for (int mt = 0; mt < 4; ++mt) {
            long base = ((long)(b * 16 + n16) * 128 + pq * 16 + wv * 4 + mt) * 128
                        + qq * 16 + quad * 4;
            if (isf32) {
                f32x4 v = {nxv[mt * 4], nxv[mt * 4 + 1], nxv[mt * 4 + 2], nxv[mt * 4 + 3]};
                *(f32x4*)((float*)out + base) = v;
            } else {
                s16x4 v = {f2bs(nxv[mt * 4]), f2bs(nxv[mt * 4 + 1]),
                           f2bs(nxv[mt * 4 + 2]), f2bs(nxv[mt * 4 + 3])};
                *(s16x4*)((short*)out + base) = v;
            }
        }
        return;
    }

    __syncthreads();

    float ssum = 0.f;
#pragma unroll
    for (int mt = 0; mt < 4; ++mt)
#pragma unroll
        for (int r = 0; r < 4; ++r) {
            int k = mt * 4 + r;
            ssum += nxv[k];
            int p = (wv * 4 + mt + 1) * 18 + quad * 4 + r + 1;
            sAH[p * SAH_STRIDE + n16] = f2bs(nxv[k]);
        }
    ssum += __shfl_xor(ssum, 16, 64);
    ssum += __shfl_xor(ssum, 32, 64);
    if (lane < 16) xred[wv * 16 + lane] = ssum;
    __syncthreads();

    float bm_l = Wf[3392 + n16];
    f32x4 accM[4];
#pragma unroll
    for (int mt = 0; mt < 4; ++mt) accM[mt] = (f32x4){bm_l, bm_l, bm_l, bm_l};
#pragma unroll
    for (int sp = 0; sp < 5; ++sp) {
        bf16x8 Bf = *(const bf16x8*)(WmS + sp * 512 + lane * 8);
        int s2 = sp * 2 + (quad >> 1);
        if (s2 > 8) s2 = 8;
        int ky = s2 / 3, kx = s2 - (s2 / 3) * 3;
        int cib = (quad & 1) * 8;
#pragma unroll
        for (int mt = 0; mt < 4; ++mt) {
            int pc = (wv * 4 + mt + ky) * 18 + n16 + kx;
            bf16x8 A = *(const bf16x8*)(sAH + pc * SAH_STRIDE + cib);
            accM[mt] = __builtin_amdgcn_mfma_f32_16x16x32_bf16(A, Bf, accM[mt], 0, 0, 0);
        }
    }
    {
        float* mo = Mout + bn * 4096;
#pragma unroll
        for (int mt = 0; mt < 4; ++mt)
#pragma unroll
            for (int r = 0; r < 4; ++r) {
                int pix = (wv * 4 + mt) * 16 + quad * 4 + r;
                mo[pix * 16 + n16] = accM[mt][r];
            }
    }
    {
        const short* row = sAH + pp * SAH_STRIDE;
        short* xo = Xout + bn * 4096 + t * 16;
        *(bf16x8*)(xo) = *(const bf16x8*)(row);
        *(bf16x8*)(xo + 8) = *(const bf16x8*)(row + 8);
    }
    if (t < 64) {
        int d = t & 31;
        const float* W = (t < 32) ? Wf : Wf + 544;
        float a = (t < 32) ? Wf[512 + d] : Wf[1056 + d];
#pragma unroll
        for (int c = 0; c < 16; ++c) {
            float xc = (xred[c] + xred[16 + c] + xred[32 + c] + xred[48 + c]) * (1.f / 256.f);
            a += xc * W[c * 32 + d];
        }
        if (t < 32) qout[bn * 32 + d] = a; else kout[bn * 32 + d] = a;
    }
}

extern "C" void kernel_launch(void* const* d_in, const int* in_sizes, int n_in,
                              void* d_out, int out_size, void* d_ws, size_t ws_size,
                              hipStream_t stream)
{
    const void* seed = d_in[0];
    const int* edge = (const int*)d_in[1];
    int E = in_sizes[1] / 2;  // 224

    float* ws = (float*)d_ws;
    short* Xb0 = (short*)ws;                         // 8 MB
    short* Xb1 = (short*)(ws + 2097152);             // 8 MB
    float* qv0 = ws + 4194304;                       // 32768 each
    float* kv0 = qv0 + 32768;
    float* qv1 = kv0 + 32768;
    float* kv1 = qv1 + 32768;
    float* Tpix = kv1 + 32768;                       // 4096
    float* Wf = Tpix + 4096;                         // 25681
    int* nbrs = (int*)(ws + 4355168);                // 256 ints, 16B-aligned
    int* counts = nbrs + 256;                        // 64
    int* flag = counts + 64;                         // 1
    __hip_bfloat16* swz = (__hip_bfloat16*)(ws + 4355600);  // 16384 bf16
    float* Mb0 = ws + 4363792;                       // 16 MB fp32
    float* Mb1 = ws + 8558096;                       // 16 MB fp32

    const short* WgS = (const short*)swz;
    const short* WcS = (const short*)(swz + 9216);
    const short* WmS = (const short*)(swz + 13824);

    // ---- HOST-SIDE coop viability check (pure queries, capture-safe, cached).
    // R11: guard rebuilt on the two facts that matter. (1) Occupancy API says
    // >=4 blocks/CU (with (256,4) pinning this is enforced by the compiler;
    // the API accounts for regs AND LDS) => 1024-block grid exactly
    // co-resident => launch cannot be rejected (R4 proved acceptance at this
    // grid/LDS shape). (2) localSizeBytes <= 64: tolerates benign allocator
    // scratch (R10's ==0 check was likely vetoing a config whose R3 baseline
    // twin performs perfectly) while still excluding R4-scale spill by 3
    // orders of magnitude. numRegs and prop.cooperativeLaunch removed.
    static int coop_ok = -1;
    if (coop_ok < 0) {
        int dev = 0, ncu = 0, nb = 0;
        hipFuncAttributes attr;
        hipError_t e1 = hipGetDevice(&dev);
        hipDeviceProp_t prop;
        hipError_t e2 = (e1 == hipSuccess) ? hipGetDeviceProperties(&prop, dev) : e1;
        hipError_t e3 = hipFuncGetAttributes(&attr, (const void*)iter4_kernel);
        hipError_t e4 = hipOccupancyMaxActiveBlocksPerMultiprocessor(
            &nb, reinterpret_cast<const void*>(iter4_kernel), 256, 0);
        if (e2 == hipSuccess) ncu = prop.multiProcessorCount;
        coop_ok = (e2 == hipSuccess && e3 == hipSuccess && e4 == hipSuccess &&
                   attr.localSizeBytes <= 64 &&
                   (long)nb * ncu >= (long)(Bt * Nt)) ? 1 : 0;
        (void)hipGetLastError();   // clear any sticky error from the queries
    }

    // Setup is identical on both paths.
    setup_kernel<<<Bt * Nt, 256, 0, stream>>>(
        seed,
        d_in[2], d_in[3], d_in[4], d_in[5], d_in[6], d_in[7], d_in[8], d_in[9],
        d_in[10], d_in[11], d_in[12], d_in[13], d_in[14], d_in[15], d_in[16],
        d_in[17], d_in[18], d_in[19],
        edge, E, Wf, Tpix, counts, nbrs, swz, Xb0, qv0, kv0, Mb0, flag);

    if (coop_ok == 1) {
        const short* Xin = Xb0;
        void* outp = d_out;
        void* kargs[] = {
            (void*)&Xin,
            (void*)&Mb0, (void*)&Mb1,
            (void*)&qv0, (void*)&kv0, (void*)&qv1, (void*)&kv1,
            (void*)&Tpix, (void*)&WmS, (void*)&WgS, (void*)&WcS, (void*)&Wf,
            (void*)&counts, (void*)&nbrs, (void*)&flag, (void*)&outp
        };
        hipError_t rc = hipLaunchCooperativeKernel(
            (const void*)iter4_kernel, dim3(Bt * Nt), dim3(256), kargs, 0, stream);
        if (rc == hipSuccess) return;
        (void)hipGetLastError();
        coop_ok = 0;   // fall through to the verified dispatch path
    }

    short* Xs[2] = {Xb0, Xb1};
    float* Ms[2] = {Mb0, Mb1};
    float* qs[2] = {qv0, qv1};
    float* ks[2] = {kv0, kv1};
    for (int it = 0; it < KITERt; ++it) {
        int in = it & 1, on = in ^ 1;
        int last = (it == KITERt - 1);
        iter_kernel<<<Bt * Nt, 256, 0, stream>>>(
            Xs[in], Xs[on], Ms[in], Ms[on], qs[in], ks[in], qs[on], ks[on],
            Tpix, WmS, WgS, WcS, Wf, counts, nbrs, flag, d_out, last);
    }
}